// Round 3
// baseline (13739.619 us; speedup 1.0000x reference)
//
#include <hip/hip_runtime.h>

// ---------------------------------------------------------------------------
// VQVAE forward, MI355X. Round 3: runtime dtype probe (fp32 vs bf16 inputs).
// Rounds 1-2 NaN'd identically across unrelated layout changes -> inputs are
// most likely fp32 (reference is pure-fp32 jax); reading fp32 as u16 halves
// makes +-1e38 junk -> inf-inf = NaN in GEMM accumulation. A device-side
// probe on enc_embed picks the decode path; outputs use the same flag.
// Internal compute: fp32. d_ws use ~39MB. Big transients live in d_out's
// logits region (written last, fully overwritten by the final GEMM).
// B=128 T=64 V=10000 NI=512 ENC_NH=640 DEC_NH=1024 NZ=128 ND=8 K=1024 D=160
// ---------------------------------------------------------------------------

typedef unsigned short u16;
typedef unsigned int u32;

__device__ __forceinline__ float b2f(u16 u) {
    union { u32 i; float f; } v; v.i = ((u32)u) << 16; return v.f;
}
__device__ __forceinline__ u16 f2b(float f) {
    union { float f; u32 i; } v; v.f = f;
    u32 x = v.i;
    u32 r = x + 0x7FFFu + ((x >> 16) & 1u);  // RNE
    return (u16)(r >> 16);
}
__device__ __forceinline__ float sigmoidf(float x) {
    return 1.0f / (1.0f + expf(-x));
}
// flag: 1 = inputs/outputs bf16, 0 = fp32
__device__ __forceinline__ float ldin(const void* p, size_t i, int bf) {
    return bf ? b2f(((const u16*)p)[i]) : ((const float*)p)[i];
}
__device__ __forceinline__ void stout(void* p, size_t i, float v, int bf) {
    if (bf) ((u16*)p)[i] = f2b(v); else ((float*)p)[i] = v;
}

// ---------------------------------------------------------------------------
// Dtype probe: even-indexed u16s of enc_embed. bf16 data ~N(0,0.05): exponent
// field in [100,127] for essentially all samples. fp32 data: even u16s are
// low mantissa halves -> uniform exponent field (~11% in range).
// ---------------------------------------------------------------------------
__global__ void probe_dtype(const void* emb, int* flag)
{
    __shared__ int cnt[128];
    int tid = threadIdx.x;
    u16 u = ((const u16*)emb)[2 * tid];
    int e = (u >> 7) & 0xFF;
    cnt[tid] = (e >= 100 && e <= 127) ? 1 : 0;
    __syncthreads();
    for (int s = 64; s > 0; s >>= 1) {
        if (tid < s) cnt[tid] += cnt[tid + s];
        __syncthreads();
    }
    if (tid == 0) *flag = (cnt[0] >= 96) ? 1 : 0;
}

__global__ void zero_kernel(float* p, int n)
{
    int i = blockIdx.x * 256 + threadIdx.x;
    if (i < n) p[i] = 0.0f;
}

// ---------------------------------------------------------------------------
// C(M,N) = A(M,K fp32, row stride lda) @ W(N,K input-dtype)^T [+ bias(N)]
// FINAL=0: C fp32 (scratch). FINAL=1: C is d_out, dtype per flag.
// M mult of 64, K mult of 16; N bounds-checked.
// ---------------------------------------------------------------------------
template <int FINAL>
__global__ __launch_bounds__(256) void gemm_kernel(
    const float* __restrict__ A, int lda,
    const void* __restrict__ Wv,
    const void* __restrict__ biasv,
    void* __restrict__ Cv, int ldc,
    int M, int N, int K, const int* __restrict__ flagp)
{
    __shared__ float As[16][68];   // [k][m], +4 pad
    __shared__ float Ws[16][68];   // [k][n]

    const int bf   = *flagp;
    const int tid  = threadIdx.x;
    const int tx   = tid & 15;
    const int ty   = tid >> 4;
    const int row0 = blockIdx.y << 6;
    const int col0 = blockIdx.x << 6;
    const int lm   = tid >> 2;        // 0..63
    const int lk   = (tid & 3) << 2;  // 0,4,8,12

    const float* Ap = A + (size_t)(row0 + lm) * lda + lk;
    const int wn    = col0 + lm;
    const bool wok  = wn < N;
    const size_t woff = (size_t)(wok ? wn : 0) * K + lk;

    float acc[4][4];
#pragma unroll
    for (int i = 0; i < 4; i++)
#pragma unroll
        for (int j = 0; j < 4; j++) acc[i][j] = 0.0f;

    for (int kt = 0; kt < K; kt += 16) {
        float4 av = *reinterpret_cast<const float4*>(Ap + kt);
        float w0 = 0.f, w1 = 0.f, w2 = 0.f, w3 = 0.f;
        if (wok) {
            if (bf) {
                ushort4 wv = *reinterpret_cast<const ushort4*>((const u16*)Wv + woff + kt);
                w0 = b2f(wv.x); w1 = b2f(wv.y); w2 = b2f(wv.z); w3 = b2f(wv.w);
            } else {
                float4 wv = *reinterpret_cast<const float4*>((const float*)Wv + woff + kt);
                w0 = wv.x; w1 = wv.y; w2 = wv.z; w3 = wv.w;
            }
        }
        As[lk + 0][lm] = av.x; As[lk + 1][lm] = av.y;
        As[lk + 2][lm] = av.z; As[lk + 3][lm] = av.w;
        Ws[lk + 0][lm] = w0; Ws[lk + 1][lm] = w1;
        Ws[lk + 2][lm] = w2; Ws[lk + 3][lm] = w3;
        __syncthreads();
#pragma unroll
        for (int kk = 0; kk < 16; kk++) {
            float a4[4], b4[4];
#pragma unroll
            for (int i = 0; i < 4; i++) a4[i] = As[kk][(ty << 2) + i];
#pragma unroll
            for (int j = 0; j < 4; j++) b4[j] = Ws[kk][(tx << 2) + j];
#pragma unroll
            for (int i = 0; i < 4; i++)
#pragma unroll
                for (int j = 0; j < 4; j++) acc[i][j] += a4[i] * b4[j];
        }
        __syncthreads();
    }

#pragma unroll
    for (int i = 0; i < 4; i++) {
        const int r = row0 + (ty << 2) + i;
#pragma unroll
        for (int j = 0; j < 4; j++) {
            const int cc = col0 + (tx << 2) + j;
            if (cc < N) {
                float v = acc[i][j];
                if (biasv) v += ldin(biasv, cc, bf);
                if (FINAL) stout(Cv, (size_t)r * ldc + cc, v, bf);
                else       ((float*)Cv)[(size_t)r * ldc + cc] = v;
            }
        }
    }
}

// we[r,i] = enc_embed[x[r],i]; werev[b*64+(63-t), i] = we[b*64+t, i]
__global__ void gather_enc(const int* __restrict__ x, const void* __restrict__ emb,
                           float* __restrict__ we, float* __restrict__ werev,
                           const int* __restrict__ flagp)
{
    int bf = *flagp;
    int idx = blockIdx.x * 256 + threadIdx.x;
    int r = idx >> 9, i = idx & 511;
    float v = ldin(emb, (size_t)x[r] * 512 + i, bf);
    we[idx] = v;
    int b = r >> 6, t = r & 63;
    werev[(((size_t)(b * 64 + (63 - t))) << 9) + i] = v;
}

// demb[r,i] = dec_embed[x[r],i] + suffix[b,i]
__global__ void demb_kernel(const int* __restrict__ x, const void* __restrict__ emb,
                            const float* __restrict__ suffix, float* __restrict__ out,
                            const int* __restrict__ flagp)
{
    int bf = *flagp;
    int idx = blockIdx.x * 256 + threadIdx.x;
    int r = idx >> 9, i = idx & 511;
    out[idx] = ldin(emb, (size_t)x[r] * 512 + i, bf) + suffix[((size_t)(r >> 6) << 9) + i];
}

// One LSTM step: g = gbuf + xg[:,t]; gates; update h,c; optional fp32 h dump.
__global__ void lstm_gate(const float* __restrict__ gbuf, const float* __restrict__ xg,
                          float* __restrict__ h, float* __restrict__ c,
                          float* __restrict__ outh, int H, int t, int T)
{
    int idx = blockIdx.x * 256 + threadIdx.x;
    if (idx >= 128 * H) return;
    int b = idx / H, j = idx - b * H;
    const float* xr = xg + (size_t)(b * T + t) * (4 * H);
    const float* gr = gbuf + (size_t)b * (4 * H);
    float gi = gr[j]         + xr[j];
    float gf = gr[H + j]     + xr[H + j];
    float gg = gr[2 * H + j] + xr[2 * H + j];
    float go = gr[3 * H + j] + xr[3 * H + j];
    float cv = sigmoidf(gf) * c[idx] + sigmoidf(gi) * tanhf(gg);
    float hv = sigmoidf(go) * tanhf(cv);
    c[idx] = cv;
    h[idx] = hv;
    if (outh) outh[(size_t)(b * T + t) * H + j] = hv;
}

__global__ void copy_h(const float* __restrict__ h, float* __restrict__ fhs, int H, int off)
{
    int idx = blockIdx.x * 256 + threadIdx.x;
    if (idx >= 128 * H) return;
    int b = idx / H, j = idx - b * H;
    fhs[b * 1280 + off + j] = h[idx];
}

__global__ void dec_init(const float* __restrict__ root, float* __restrict__ h, float* __restrict__ c)
{
    int idx = blockIdx.x * 256 + threadIdx.x;  // 128*1024
    float r = root[idx];
    h[idx] = tanhf(r);
    c[idx] = r;
}

// kl[b] = 0.5*sum_j(mu^2 + exp(lv) - lv - 1) -> out element OFF_KL+b
__global__ void kl_kernel(const float* __restrict__ ml, void* __restrict__ outv,
                          const int* __restrict__ flagp)
{
    const size_t OFF_KL = 81920128;
    int b = blockIdx.x, j = threadIdx.x;
    float mu = ml[b * 256 + j];
    float lv = ml[b * 256 + 128 + j];
    float v = mu * mu + expf(lv) - lv - 1.0f;
    __shared__ float red[128];
    red[j] = v; __syncthreads();
    for (int s = 64; s > 0; s >>= 1) {
        if (j < s) red[j] += red[j + s];
        __syncthreads();
    }
    if (j == 0) stout(outv, OFF_KL + b, 0.5f * red[0], *flagp);
}

// Per (b,n): argmin_k ||lat||^2 + ||cb||^2 - 2 lat.cb; gather q; vq partials.
__global__ __launch_bounds__(256) void vq_kernel(
    const float* __restrict__ fhs, const void* __restrict__ cbs,
    float* __restrict__ q, float* __restrict__ vq_accum, void* __restrict__ outv,
    const int* __restrict__ flagp)
{
    const size_t OFF_IND = 81920256;
    int bf = *flagp;
    int bn = blockIdx.x;
    int b = bn >> 3, n = bn & 7;
    __shared__ float lat[160];
    __shared__ float ssc[256];
    __shared__ int   sid[256];
    __shared__ float slat2;
    __shared__ int   bestk;
    int tid = threadIdx.x;
    if (tid < 160) lat[tid] = fhs[b * 1280 + n * 160 + tid];
    __syncthreads();
    ssc[tid] = (tid < 160) ? lat[tid] * lat[tid] : 0.0f;
    __syncthreads();
    for (int s = 128; s > 0; s >>= 1) {
        if (tid < s) ssc[tid] += ssc[tid + s];
        __syncthreads();
    }
    if (tid == 0) slat2 = ssc[0];
    __syncthreads();
    float l2 = slat2;

    float best = 3.4e38f; int bi = 0;
    for (int k = tid; k < 1024; k += 256) {
        size_t cbase = (size_t)(n * 1024 + k) * 160;
        float dot = 0.0f, c2 = 0.0f;
        for (int d = 0; d < 160; d++) {
            float f = ldin(cbs, cbase + d, bf);
            dot += lat[d] * f;
            c2  += f * f;
        }
        float s = l2 + c2 - 2.0f * dot;
        if (s < best) { best = s; bi = k; }
    }
    ssc[tid] = best; sid[tid] = bi;
    __syncthreads();
    for (int s = 128; s > 0; s >>= 1) {
        if (tid < s) {
            float o = ssc[tid + s]; int oi = sid[tid + s];
            if (o < ssc[tid] || (o == ssc[tid] && oi < sid[tid])) { ssc[tid] = o; sid[tid] = oi; }
        }
        __syncthreads();
    }
    if (tid == 0) { bestk = sid[0]; stout(outv, OFF_IND + bn, (float)sid[0], bf); }
    __syncthreads();

    float part = 0.0f;
    if (tid < 160) {
        float qv = ldin(cbs, (size_t)(n * 1024 + bestk) * 160 + tid, bf);
        q[b * 1280 + n * 160 + tid] = qv;
        float df = qv - lat[tid];
        part = df * df;
    }
    ssc[tid] = part;
    __syncthreads();
    for (int s = 128; s > 0; s >>= 1) {
        if (tid < s) ssc[tid] += ssc[tid + s];
        __syncthreads();
    }
    if (tid == 0) atomicAdd(&vq_accum[b], ssc[0]);
}

// vq_loss[b] = (1+BETA) * accum / 160 -> out element OFF_VQ+b
__global__ void vq_fin(const float* __restrict__ vq_accum, void* __restrict__ outv,
                       const int* __restrict__ flagp)
{
    const size_t OFF_VQ = 81920000;
    int b = threadIdx.x;  // 128
    stout(outv, OFF_VQ + b, vq_accum[b] * (1.25f / 160.0f), *flagp);
}

// ---------------------------------------------------------------------------

extern "C" void kernel_launch(void* const* d_in, const int* in_sizes, int n_in,
                              void* d_out, int out_size, void* d_ws, size_t ws_size,
                              hipStream_t stream)
{
    const int*  x         = (const int*)d_in[0];
    const void* enc_embed = d_in[1];
    const void* enc_Wih_f = d_in[2];
    const void* enc_Whh_f = d_in[3];
    const void* enc_b_f   = d_in[4];
    const void* enc_Wih_b = d_in[5];
    const void* enc_Whh_b = d_in[6];
    const void* enc_b_b   = d_in[7];
    const void* enc_lin   = d_in[8];
    const void* z2dec_W   = d_in[9];
    const void* z2dec_b   = d_in[10];
    const void* codebooks = d_in[11];
    const void* suffix_W  = d_in[12];
    const void* dec_embed = d_in[13];
    const void* dec_Wih   = d_in[14];
    const void* dec_Whh   = d_in[15];
    const void* dec_b     = d_in[16];
    const void* pred_W    = d_in[17];

    // ---- scratch inside d_out's logits region (>=163.8MB; dead before the
    //      final GEMM, which overwrites it) ----
    char* ob = (char*)d_out;
    float* xg    = (float*)(ob + 0);              // dec: 8192x4096 f32 = 128MB
                                                  // enc: 8192x2560 f32 =  80MB
    float* we    = (float*)(ob + 83886080);       // enc phase, 16MB
    float* werev = (float*)(ob + 100663296);      // enc phase, 16MB
    float* demb  = (float*)(ob + 134217728);      // dec phase, 16MB (ends 151MB)

    // ---- d_ws: ~39MB ----
    char* wb = (char*)d_ws;
    float* decout = (float*)(wb + 0);             // 8192x1024 f32 = 33,554,432
    float* g      = (float*)(wb + 33554432);      // 128x4096 f32
    float* h      = (float*)(wb + 35651584);      // 128x1024 f32  (h,c contiguous)
    float* c      = (float*)(wb + 36175872);      // 128x1024 f32
    float* fhs    = (float*)(wb + 36700160);      // 128x1280 f32
    float* ml     = (float*)(wb + 37355520);      // 128x256  f32
    float* root   = (float*)(wb + 37486592);      // 128x1024 f32
    float* q      = (float*)(wb + 38010880);      // 128x1280 f32
    float* suffix = (float*)(wb + 38666240);      // 128x512  f32
    float* vqa    = (float*)(wb + 38928384);      // 128 f32
    int*   flag   = (int*)  (wb + 38928896);      // 1 int

    // dtype probe + zero-init (h,c contiguous: 262144 floats; vqa 128)
    probe_dtype<<<1, 128, 0, stream>>>(enc_embed, flag);
    zero_kernel<<<1024, 256, 0, stream>>>(h, 262144);
    zero_kernel<<<1, 128, 0, stream>>>(vqa, 128);

    // embeddings (forward + time-reversed)
    gather_enc<<<16384, 256, 0, stream>>>(x, enc_embed, we, werev, flag);

    // xg_f = we @ enc_Wih_f^T + b  (8192x2560)
    gemm_kernel<0><<<dim3(40, 128), 256, 0, stream>>>(we, 512, enc_Wih_f, enc_b_f,
                                                      xg, 2560, 8192, 2560, 512, flag);
    for (int t = 0; t < 64; t++) {
        gemm_kernel<0><<<dim3(40, 2), 256, 0, stream>>>(h, 640, enc_Whh_f, nullptr,
                                                        g, 2560, 128, 2560, 640, flag);
        lstm_gate<<<320, 256, 0, stream>>>(g, xg, h, c, nullptr, 640, t, 64);
    }
    copy_h<<<320, 256, 0, stream>>>(h, fhs, 640, 0);

    // backward direction
    zero_kernel<<<1024, 256, 0, stream>>>(h, 262144);
    gemm_kernel<0><<<dim3(40, 128), 256, 0, stream>>>(werev, 512, enc_Wih_b, enc_b_b,
                                                      xg, 2560, 8192, 2560, 512, flag);
    for (int t = 0; t < 64; t++) {
        gemm_kernel<0><<<dim3(40, 2), 256, 0, stream>>>(h, 640, enc_Whh_b, nullptr,
                                                        g, 2560, 128, 2560, 640, flag);
        lstm_gate<<<320, 256, 0, stream>>>(g, xg, h, c, nullptr, 640, t, 64);
    }
    copy_h<<<320, 256, 0, stream>>>(h, fhs, 640, 640);

    // mu|logvar = fhs @ enc_lin^T  (128x256)
    gemm_kernel<0><<<dim3(4, 2), 256, 0, stream>>>(fhs, 1280, enc_lin, nullptr,
                                                   ml, 256, 128, 256, 1280, flag);
    kl_kernel<<<128, 128, 0, stream>>>(ml, d_out, flag);

    // root = mu @ z2dec_W^T + b  (mu = ml cols 0..127, lda 256)
    gemm_kernel<0><<<dim3(16, 2), 256, 0, stream>>>(ml, 256, z2dec_W, z2dec_b,
                                                    root, 1024, 128, 1024, 128, flag);

    vq_kernel<<<1024, 256, 0, stream>>>(fhs, codebooks, q, vqa, d_out, flag);
    vq_fin<<<1, 128, 0, stream>>>(vqa, d_out, flag);

    // suffix = q @ suffix_W^T  (128x512)
    gemm_kernel<0><<<dim3(8, 2), 256, 0, stream>>>(q, 1280, suffix_W, nullptr,
                                                   suffix, 512, 128, 512, 1280, flag);

    // demb = dec_embed[x] + suffix
    demb_kernel<<<16384, 256, 0, stream>>>(x, dec_embed, suffix, demb, flag);

    // xg_d = demb @ dec_Wih^T + b  (8192x4096)
    gemm_kernel<0><<<dim3(64, 128), 256, 0, stream>>>(demb, 512, dec_Wih, dec_b,
                                                      xg, 4096, 8192, 4096, 512, flag);

    // decoder LSTM: h0 = tanh(root), c0 = root; dump fp32 h into decout
    dec_init<<<512, 256, 0, stream>>>(root, h, c);
    for (int t = 0; t < 64; t++) {
        gemm_kernel<0><<<dim3(64, 2), 256, 0, stream>>>(h, 1024, dec_Whh, nullptr,
                                                        g, 4096, 128, 4096, 1024, flag);
        lstm_gate<<<512, 256, 0, stream>>>(g, xg, h, c, decout, 1024, t, 64);
    }

    // logits = decout @ pred_W^T -> d_out (dtype per flag; overwrites scratch)
    gemm_kernel<1><<<dim3(157, 128), 256, 0, stream>>>(decout, 1024, pred_W, nullptr,
                                                       d_out, 10000, 8192, 10000, 1024, flag);
}